// Round 2
// baseline (88.092 us; speedup 1.0000x reference)
//
#include <hip/hip_runtime.h>
#include <cstdint>
#include <cstddef>

// Problem constants: B=16, S=512, DEG=8, D=512, L=64
#define DDIM   512
#define NNODES 8192      // B*S
#define NEDGE  65536     // B*S*DEG
#define KDIM   1664      // 3*D + 2*L  (a_in | a_out | a_loop | hist_in | hist_out)

typedef __attribute__((ext_vector_type(8))) short bf16x8;
typedef __attribute__((ext_vector_type(4))) float f32x4;

static __device__ __forceinline__ unsigned short f2bf(float f) {
    unsigned u = __float_as_uint(f);
    u += 0x7FFFu + ((u >> 16) & 1u);   // round-to-nearest-even
    return (unsigned short)(u >> 16);
}

static __device__ __forceinline__ void unpack8(uint4 pv, float* pf) {
    const unsigned* pw = (const unsigned*)&pv;
    pf[0] = __uint_as_float(pw[0] << 16); pf[1] = __uint_as_float(pw[0] & 0xffff0000u);
    pf[2] = __uint_as_float(pw[1] << 16); pf[3] = __uint_as_float(pw[1] & 0xffff0000u);
    pf[4] = __uint_as_float(pw[2] << 16); pf[5] = __uint_as_float(pw[2] & 0xffff0000u);
    pf[6] = __uint_as_float(pw[3] << 16); pf[7] = __uint_as_float(pw[3] & 0xffff0000u);
}

// ---------------------------------------------------------------------------
// Kernel 1: x -> bf16 (xb) + three per-node gate dot products.
// One wave per row; lane j handles columns 8j..8j+7.
// ---------------------------------------------------------------------------
__global__ __launch_bounds__(256) void prep_kernel(
    const float* __restrict__ src,
    const float* __restrict__ vg_in, const float* __restrict__ vg_out,
    const float* __restrict__ vg_loop,
    unsigned short* __restrict__ xb,
    float* __restrict__ g_in, float* __restrict__ g_out, float* __restrict__ g_loop)
{
    int lane = threadIdx.x & 63;
    int row  = blockIdx.x * 4 + (threadIdx.x >> 6);
    int j0   = lane * 8;

    const float* x = src + (size_t)row * DDIM + j0;
    float4 x0 = *(const float4*)x;
    float4 x1 = *(const float4*)(x + 4);
    float xs[8] = {x0.x, x0.y, x0.z, x0.w, x1.x, x1.y, x1.z, x1.w};

    alignas(16) unsigned short h[8];
#pragma unroll
    for (int i = 0; i < 8; ++i) h[i] = f2bf(xs[i]);
    *(uint4*)(xb + (size_t)row * DDIM + j0) = *(const uint4*)h;

    float s0 = 0.f, s1 = 0.f, s2 = 0.f;
#pragma unroll
    for (int i = 0; i < 8; ++i) {
        s0 += xs[i] * vg_in[j0 + i];
        s1 += xs[i] * vg_out[j0 + i];
        s2 += xs[i] * vg_loop[j0 + i];
    }
#pragma unroll
    for (int o = 32; o > 0; o >>= 1) {
        s0 += __shfl_xor(s0, o);
        s1 += __shfl_xor(s1, o);
        s2 += __shfl_xor(s2, o);
    }
    if (lane == 0) { g_in[row] = s0; g_out[row] = s1; g_loop[row] = s2; }
}

// ---------------------------------------------------------------------------
// Kernel 2: build stacked weight, transposed N-major:
//   WbT[n][k] = Wstack[k][n], k: 0..511 V_in, 512..1023 V_out,
//   1024..1535 W_loop, 1536..1599 b_in, 1600..1663 b_out.
// 64x64 tile transpose through LDS; all segment boundaries are 64-aligned.
// ---------------------------------------------------------------------------
__global__ __launch_bounds__(256) void wstack_kernel(
    const float* __restrict__ v_in, const float* __restrict__ v_out,
    const float* __restrict__ w_loop, const float* __restrict__ b_in,
    const float* __restrict__ b_out, unsigned short* __restrict__ wbt)
{
    __shared__ float tile[64][65];
    int kt = blockIdx.x / 8;          // 0..25
    int nt = blockIdx.x % 8;          // 0..7
    int k0 = kt * 64, n0 = nt * 64;

    const float* srcp; int kbase;
    if      (kt < 8)  { srcp = v_in;   kbase = 0; }
    else if (kt < 16) { srcp = v_out;  kbase = 512; }
    else if (kt < 24) { srcp = w_loop; kbase = 1024; }
    else if (kt == 24){ srcp = b_in;   kbase = 1536; }
    else              { srcp = b_out;  kbase = 1600; }

    int c  = threadIdx.x & 63;
    int rr = threadIdx.x >> 6;        // 0..3
#pragma unroll
    for (int i = 0; i < 16; ++i) {
        int kk = i * 4 + rr;
        tile[kk][c] = srcp[(size_t)(k0 + kk - kbase) * DDIM + n0 + c];
    }
    __syncthreads();
#pragma unroll
    for (int i = 0; i < 16; ++i) {
        int nn = i * 4 + rr;
        wbt[(size_t)(n0 + nn) * KDIM + k0 + c] = f2bf(tile[c][nn]);
    }
}

// ---------------------------------------------------------------------------
// Kernel 3: gather-aggregate in x-space. One wave per node.
// A[n] = [ sum_k w_in_k * x[src_k] | sum_k w_out_k * x[src_k] | w_loop*x[n] |
//          hist_in[64] | hist_out[64] ]   (bf16, KDIM=1664)
// ---------------------------------------------------------------------------
__global__ __launch_bounds__(256) void aggx_kernel(
    const unsigned short* __restrict__ xb,
    const float* __restrict__ g_in, const float* __restrict__ g_out,
    const float* __restrict__ g_loop,
    const int* __restrict__ arc_in, const int* __restrict__ lbl_in,
    const int* __restrict__ arc_out, const int* __restrict__ lbl_out,
    const float* __restrict__ mask_in, const float* __restrict__ mask_out,
    const float* __restrict__ mask_loop,
    const float* __restrict__ bg_in, const float* __restrict__ bg_out,
    unsigned short* __restrict__ A)
{
    int lane = threadIdx.x & 63;
    int n    = blockIdx.x * 4 + (threadIdx.x >> 6);
    int j0   = lane * 8;

    float acc_in[8] = {0,0,0,0,0,0,0,0};
    float acc_out[8] = {0,0,0,0,0,0,0,0};
    float hin = 0.f, hout = 0.f;

#pragma unroll
    for (int k = 0; k < 8; ++k) {
        int e  = n * 8 + k;
        int sn = arc_in[e] * 512 + arc_in[NEDGE + e];
        int lb = lbl_in[e];
        float w = mask_in[e] / (1.0f + __expf(-(g_in[sn] + bg_in[lb])));
        uint4 pv = *(const uint4*)(xb + (size_t)sn * DDIM + j0);
        float pf[8]; unpack8(pv, pf);
#pragma unroll
        for (int i = 0; i < 8; ++i) acc_in[i] += w * pf[i];
        hin += (lb == lane) ? w : 0.f;
    }
#pragma unroll
    for (int k = 0; k < 8; ++k) {
        int e  = n * 8 + k;
        int sn = arc_out[e] * 512 + arc_out[NEDGE + e];
        int lb = lbl_out[e];
        float w = mask_out[e] / (1.0f + __expf(-(g_out[sn] + bg_out[lb])));
        uint4 pv = *(const uint4*)(xb + (size_t)sn * DDIM + j0);
        float pf[8]; unpack8(pv, pf);
#pragma unroll
        for (int i = 0; i < 8; ++i) acc_out[i] += w * pf[i];
        hout += (lb == lane) ? w : 0.f;
    }
    float wl = mask_loop[n] / (1.0f + __expf(-g_loop[n]));
    uint4 own = *(const uint4*)(xb + (size_t)n * DDIM + j0);
    float lp[8]; unpack8(own, lp);

    unsigned short* Ar = A + (size_t)n * KDIM;
    alignas(16) unsigned short h[8];
#pragma unroll
    for (int i = 0; i < 8; ++i) h[i] = f2bf(acc_in[i]);
    *(uint4*)(Ar + j0) = *(const uint4*)h;
#pragma unroll
    for (int i = 0; i < 8; ++i) h[i] = f2bf(acc_out[i]);
    *(uint4*)(Ar + 512 + j0) = *(const uint4*)h;
#pragma unroll
    for (int i = 0; i < 8; ++i) h[i] = f2bf(wl * lp[i]);
    *(uint4*)(Ar + 1024 + j0) = *(const uint4*)h;
    Ar[1536 + lane] = f2bf(hin);
    Ar[1600 + lane] = f2bf(hout);
}

// ---------------------------------------------------------------------------
// Kernel 4: GEMM  H[8192 x 512] = A[8192 x 1664] @ Wstack[1664 x 512]
// 128x128 tile, BK=32, 512 threads (8 waves, 4m x 2n, each 32x64),
// one global_load_lds(16B) per operand per thread per K-step.
// LDS layout [kb][row][8] — linear in staging order, conflict-free b128 reads.
// Grid 256 with XCD-chunked swizzle (256 = 8 XCD x 32).
// ---------------------------------------------------------------------------
__global__ __launch_bounds__(512) void gemm2_kernel(
    const unsigned short* __restrict__ A,
    const unsigned short* __restrict__ wbt,
    float* __restrict__ H)
{
    __shared__ short lds_a[4096];   // [4 kb][128 row][8] = 8 KB
    __shared__ short lds_b[4096];

    int tid  = threadIdx.x;
    int lane = tid & 63;
    int wid  = tid >> 6;           // 0..7
    int g    = blockIdx.x;
    int gs   = (g & 7) * 32 + (g >> 3);   // XCD-chunked swizzle (bijective: 256=8*32)
    int tm   = gs >> 2, tn = gs & 3;
    int row0 = tm * 128, col0 = tn * 128;
    int wm   = wid >> 1, wn = wid & 1;    // 4 x 2 waves, each 32 rows x 64 cols
    int r16  = lane & 15, kq = lane >> 4;

    int srow = tid & 127;          // staging row/col
    int skb  = tid >> 7;           // staging k-block (0..3)

    f32x4 acc[2][4];
#pragma unroll
    for (int m = 0; m < 2; ++m)
#pragma unroll
        for (int n = 0; n < 4; ++n) acc[m][n] = (f32x4){0.f, 0.f, 0.f, 0.f};

    const unsigned short* ga = A   + (size_t)(row0 + srow) * KDIM + skb * 8;
    const unsigned short* gb = wbt + (size_t)(col0 + srow) * KDIM + skb * 8;

    for (int kt = 0; kt < 52; ++kt) {
        int k0 = kt * 32;
        __syncthreads();
        __builtin_amdgcn_global_load_lds(
            (__attribute__((address_space(1))) void*)(uintptr_t)(ga + k0),
            (__attribute__((address_space(3))) void*)(lds_a + wid * 512), 16, 0, 0);
        __builtin_amdgcn_global_load_lds(
            (__attribute__((address_space(1))) void*)(uintptr_t)(gb + k0),
            (__attribute__((address_space(3))) void*)(lds_b + wid * 512), 16, 0, 0);
        __syncthreads();

        bf16x8 af[2], bfr[4];
#pragma unroll
        for (int m = 0; m < 2; ++m)
            af[m] = *(const bf16x8*)(lds_a + kq * 1024 + (wm * 32 + m * 16 + r16) * 8);
#pragma unroll
        for (int n = 0; n < 4; ++n)
            bfr[n] = *(const bf16x8*)(lds_b + kq * 1024 + (wn * 64 + n * 16 + r16) * 8);
#pragma unroll
        for (int m = 0; m < 2; ++m)
#pragma unroll
            for (int n = 0; n < 4; ++n)
                acc[m][n] = __builtin_amdgcn_mfma_f32_16x16x32_bf16(
                    af[m], bfr[n], acc[m][n], 0, 0, 0);
    }

    // C/D layout: col = lane&15, row = (lane>>4)*4 + reg
#pragma unroll
    for (int m = 0; m < 2; ++m) {
        int grow = row0 + wm * 32 + m * 16 + kq * 4;
#pragma unroll
        for (int n = 0; n < 4; ++n) {
            int gcol = col0 + wn * 64 + n * 16 + r16;
#pragma unroll
            for (int r = 0; r < 4; ++r)
                H[(size_t)(grow + r) * DDIM + gcol] = acc[m][n][r];
        }
    }
}

// ---------------------------------------------------------------------------
// Kernel 5: LayerNorm + relu + residual epilogue. One wave per row.
// ---------------------------------------------------------------------------
__global__ __launch_bounds__(256) void ln_kernel(
    const float* __restrict__ H, const float* __restrict__ src,
    const float* __restrict__ sent_mask,
    const float* __restrict__ ln_g, const float* __restrict__ ln_b,
    float* __restrict__ out)
{
    int lane = threadIdx.x & 63;
    int n    = blockIdx.x * 4 + (threadIdx.x >> 6);
    int j0   = lane * 8;

    const float* hr = H + (size_t)n * DDIM + j0;
    float4 h0 = *(const float4*)hr;
    float4 h1 = *(const float4*)(hr + 4);
    float hs[8] = {h0.x, h0.y, h0.z, h0.w, h1.x, h1.y, h1.z, h1.w};

    float sum = 0.f, sq = 0.f;
#pragma unroll
    for (int i = 0; i < 8; ++i) { sum += hs[i]; sq += hs[i] * hs[i]; }
#pragma unroll
    for (int o = 32; o > 0; o >>= 1) {
        sum += __shfl_xor(sum, o);
        sq  += __shfl_xor(sq, o);
    }
    float mu   = sum * (1.0f / 512.0f);
    float var  = sq * (1.0f / 512.0f) - mu * mu;
    float rstd = rsqrtf(var + 1e-5f);
    float sm   = sent_mask[n];

    float4 gg0 = *(const float4*)(ln_g + j0);
    float4 gg1 = *(const float4*)(ln_g + j0 + 4);
    float4 be0 = *(const float4*)(ln_b + j0);
    float4 be1 = *(const float4*)(ln_b + j0 + 4);
    const float* sr = src + (size_t)n * DDIM + j0;
    float4 s0 = *(const float4*)sr;
    float4 s1 = *(const float4*)(sr + 4);
    float gl[8] = {gg0.x, gg0.y, gg0.z, gg0.w, gg1.x, gg1.y, gg1.z, gg1.w};
    float bt[8] = {be0.x, be0.y, be0.z, be0.w, be1.x, be1.y, be1.z, be1.w};
    float srs[8] = {s0.x, s0.y, s0.z, s0.w, s1.x, s1.y, s1.z, s1.w};

    float o_[8];
#pragma unroll
    for (int i = 0; i < 8; ++i) {
        float v = (hs[i] - mu) * rstd * gl[i] + bt[i];
        v *= sm;
        v = fmaxf(v, 0.f);
        o_[i] = v * sm + srs[i];
    }
    float4 w0 = {o_[0], o_[1], o_[2], o_[3]};
    float4 w1 = {o_[4], o_[5], o_[6], o_[7]};
    float* op = out + (size_t)n * DDIM + j0;
    *(float4*)op = w0;
    *(float4*)(op + 4) = w1;
}

// ---------------------------------------------------------------------------
// Workspace layout (bytes):
//   xb    : 0           (8,388,608)   8192*512 bf16
//   wbt   : 8,388,608   (1,703,936)   512*1664 bf16
//   g_in  : 10,092,544  (32,768)
//   g_out : 10,125,312  (32,768)
//   g_loop: 10,158,080  (32,768)
//   Acat  : 10,190,848  (27,262,976)  8192*1664 bf16
//   H     : 37,453,824  (16,777,216)  8192*512 f32
// ---------------------------------------------------------------------------
extern "C" void kernel_launch(void* const* d_in, const int* in_sizes, int n_in,
                              void* d_out, int out_size, void* d_ws, size_t ws_size,
                              hipStream_t stream)
{
    const float* src       = (const float*)d_in[0];
    const int*   arc_in    = (const int*)d_in[1];
    const int*   lbl_in    = (const int*)d_in[2];
    const int*   arc_out   = (const int*)d_in[3];
    const int*   lbl_out   = (const int*)d_in[4];
    const float* mask_in   = (const float*)d_in[5];
    const float* mask_out  = (const float*)d_in[6];
    const float* mask_loop = (const float*)d_in[7];
    const float* sent_mask = (const float*)d_in[8];
    const float* V_in      = (const float*)d_in[9];
    const float* b_in      = (const float*)d_in[10];
    const float* Vg_in     = (const float*)d_in[11];
    const float* bg_in     = (const float*)d_in[12];
    const float* V_out     = (const float*)d_in[13];
    const float* b_out     = (const float*)d_in[14];
    const float* Vg_out    = (const float*)d_in[15];
    const float* bg_out    = (const float*)d_in[16];
    const float* W_loop    = (const float*)d_in[17];
    const float* Wg_loop   = (const float*)d_in[18];
    const float* ln_g      = (const float*)d_in[19];
    const float* ln_b      = (const float*)d_in[20];

    uint8_t* ws = (uint8_t*)d_ws;
    unsigned short* xb    = (unsigned short*)(ws);
    unsigned short* wbt   = (unsigned short*)(ws + 8388608);
    float*          g_in  = (float*)(ws + 10092544);
    float*          g_out = (float*)(ws + 10125312);
    float*          g_lp  = (float*)(ws + 10158080);
    unsigned short* Acat  = (unsigned short*)(ws + 10190848);
    float*          H     = (float*)(ws + 37453824);

    prep_kernel<<<2048, 256, 0, stream>>>(src, Vg_in, Vg_out, Wg_loop, xb, g_in, g_out, g_lp);
    wstack_kernel<<<208, 256, 0, stream>>>(V_in, V_out, W_loop, b_in, b_out, wbt);
    aggx_kernel<<<2048, 256, 0, stream>>>(xb, g_in, g_out, g_lp,
                                          arc_in, lbl_in, arc_out, lbl_out,
                                          mask_in, mask_out, mask_loop,
                                          bg_in, bg_out, Acat);
    gemm2_kernel<<<256, 512, 0, stream>>>(Acat, wbt, H);
    ln_kernel<<<2048, 256, 0, stream>>>(H, src, sent_mask, ln_g, ln_b, (float*)d_out);
}

// Round 3
// 82.221 us; speedup vs baseline: 1.0714x; 1.0714x over previous
//
#include <hip/hip_runtime.h>
#include <cstdint>
#include <cstddef>

// Problem constants: B=16, S=512, DEG=8, D=512, L=64
#define DDIM   512
#define NNODES 8192      // B*S
#define NEDGE  65536     // B*S*DEG
#define KDIM   1664      // 3*D + 2*L  (a_in | a_out | a_loop | hist_in | hist_out)

typedef __attribute__((ext_vector_type(8))) short bf16x8;
typedef __attribute__((ext_vector_type(4))) float f32x4;

static __device__ __forceinline__ unsigned short f2bf(float f) {
    unsigned u = __float_as_uint(f);
    u += 0x7FFFu + ((u >> 16) & 1u);   // round-to-nearest-even
    return (unsigned short)(u >> 16);
}

static __device__ __forceinline__ void unpack8(uint4 pv, float* pf) {
    const unsigned* pw = (const unsigned*)&pv;
    pf[0] = __uint_as_float(pw[0] << 16); pf[1] = __uint_as_float(pw[0] & 0xffff0000u);
    pf[2] = __uint_as_float(pw[1] << 16); pf[3] = __uint_as_float(pw[1] & 0xffff0000u);
    pf[4] = __uint_as_float(pw[2] << 16); pf[5] = __uint_as_float(pw[2] & 0xffff0000u);
    pf[6] = __uint_as_float(pw[3] << 16); pf[7] = __uint_as_float(pw[3] & 0xffff0000u);
}

// ---------------------------------------------------------------------------
// Kernel 1 (merged): blocks [0,2048): x->bf16 + gate dots.
//                    blocks [2048,2256): stacked-transposed bf16 weight build.
// ---------------------------------------------------------------------------
__global__ __launch_bounds__(256) void prep_kernel(
    const float* __restrict__ src,
    const float* __restrict__ vg_in, const float* __restrict__ vg_out,
    const float* __restrict__ vg_loop,
    const float* __restrict__ v_in, const float* __restrict__ v_out,
    const float* __restrict__ w_loop, const float* __restrict__ b_in,
    const float* __restrict__ b_out,
    unsigned short* __restrict__ xb, unsigned short* __restrict__ wbt,
    float* __restrict__ g_in, float* __restrict__ g_out, float* __restrict__ g_loop)
{
    __shared__ float tile[64][65];
    if (blockIdx.x < 2048) {
        int lane = threadIdx.x & 63;
        int row  = blockIdx.x * 4 + (threadIdx.x >> 6);
        int j0   = lane * 8;

        const float* x = src + (size_t)row * DDIM + j0;
        float4 x0 = *(const float4*)x;
        float4 x1 = *(const float4*)(x + 4);
        float xs[8] = {x0.x, x0.y, x0.z, x0.w, x1.x, x1.y, x1.z, x1.w};

        alignas(16) unsigned short h[8];
#pragma unroll
        for (int i = 0; i < 8; ++i) h[i] = f2bf(xs[i]);
        *(uint4*)(xb + (size_t)row * DDIM + j0) = *(const uint4*)h;

        float s0 = 0.f, s1 = 0.f, s2 = 0.f;
#pragma unroll
        for (int i = 0; i < 8; ++i) {
            s0 += xs[i] * vg_in[j0 + i];
            s1 += xs[i] * vg_out[j0 + i];
            s2 += xs[i] * vg_loop[j0 + i];
        }
#pragma unroll
        for (int o = 32; o > 0; o >>= 1) {
            s0 += __shfl_xor(s0, o);
            s1 += __shfl_xor(s1, o);
            s2 += __shfl_xor(s2, o);
        }
        if (lane == 0) { g_in[row] = s0; g_out[row] = s1; g_loop[row] = s2; }
    } else {
        int bb = blockIdx.x - 2048;
        int kt = bb / 8;              // 0..25
        int nt = bb % 8;              // 0..7
        int k0 = kt * 64, n0 = nt * 64;

        const float* srcp; int kbase;
        if      (kt < 8)  { srcp = v_in;   kbase = 0; }
        else if (kt < 16) { srcp = v_out;  kbase = 512; }
        else if (kt < 24) { srcp = w_loop; kbase = 1024; }
        else if (kt == 24){ srcp = b_in;   kbase = 1536; }
        else              { srcp = b_out;  kbase = 1600; }

        int c  = threadIdx.x & 63;
        int rr = threadIdx.x >> 6;    // 0..3
#pragma unroll
        for (int i = 0; i < 16; ++i) {
            int kk = i * 4 + rr;
            tile[kk][c] = srcp[(size_t)(k0 + kk - kbase) * DDIM + n0 + c];
        }
        __syncthreads();
#pragma unroll
        for (int i = 0; i < 16; ++i) {
            int nn = i * 4 + rr;
            wbt[(size_t)(n0 + nn) * KDIM + k0 + c] = f2bf(tile[c][nn]);
        }
    }
}

// ---------------------------------------------------------------------------
// Kernel 2: gather-aggregate in x-space. One wave per node.
// A[n] = [ sum w_in*x[src] | sum w_out*x[src] | w_loop*x[n] | hist_in | hist_out ]
// ---------------------------------------------------------------------------
__global__ __launch_bounds__(256) void aggx_kernel(
    const unsigned short* __restrict__ xb,
    const float* __restrict__ g_in, const float* __restrict__ g_out,
    const float* __restrict__ g_loop,
    const int* __restrict__ arc_in, const int* __restrict__ lbl_in,
    const int* __restrict__ arc_out, const int* __restrict__ lbl_out,
    const float* __restrict__ mask_in, const float* __restrict__ mask_out,
    const float* __restrict__ mask_loop,
    const float* __restrict__ bg_in, const float* __restrict__ bg_out,
    unsigned short* __restrict__ A)
{
    int lane = threadIdx.x & 63;
    int n    = blockIdx.x * 4 + (threadIdx.x >> 6);
    int j0   = lane * 8;

    float acc_in[8] = {0,0,0,0,0,0,0,0};
    float acc_out[8] = {0,0,0,0,0,0,0,0};
    float hin = 0.f, hout = 0.f;

#pragma unroll
    for (int k = 0; k < 8; ++k) {
        int e  = n * 8 + k;
        int sn = arc_in[e] * 512 + arc_in[NEDGE + e];
        int lb = lbl_in[e];
        float w = mask_in[e] / (1.0f + __expf(-(g_in[sn] + bg_in[lb])));
        uint4 pv = *(const uint4*)(xb + (size_t)sn * DDIM + j0);
        float pf[8]; unpack8(pv, pf);
#pragma unroll
        for (int i = 0; i < 8; ++i) acc_in[i] += w * pf[i];
        hin += (lb == lane) ? w : 0.f;
    }
#pragma unroll
    for (int k = 0; k < 8; ++k) {
        int e  = n * 8 + k;
        int sn = arc_out[e] * 512 + arc_out[NEDGE + e];
        int lb = lbl_out[e];
        float w = mask_out[e] / (1.0f + __expf(-(g_out[sn] + bg_out[lb])));
        uint4 pv = *(const uint4*)(xb + (size_t)sn * DDIM + j0);
        float pf[8]; unpack8(pv, pf);
#pragma unroll
        for (int i = 0; i < 8; ++i) acc_out[i] += w * pf[i];
        hout += (lb == lane) ? w : 0.f;
    }
    float wl = mask_loop[n] / (1.0f + __expf(-g_loop[n]));
    uint4 own = *(const uint4*)(xb + (size_t)n * DDIM + j0);
    float lp[8]; unpack8(own, lp);

    unsigned short* Ar = A + (size_t)n * KDIM;
    alignas(16) unsigned short h[8];
#pragma unroll
    for (int i = 0; i < 8; ++i) h[i] = f2bf(acc_in[i]);
    *(uint4*)(Ar + j0) = *(const uint4*)h;
#pragma unroll
    for (int i = 0; i < 8; ++i) h[i] = f2bf(acc_out[i]);
    *(uint4*)(Ar + 512 + j0) = *(const uint4*)h;
#pragma unroll
    for (int i = 0; i < 8; ++i) h[i] = f2bf(wl * lp[i]);
    *(uint4*)(Ar + 1024 + j0) = *(const uint4*)h;
    Ar[1536 + lane] = f2bf(hin);
    Ar[1600 + lane] = f2bf(hout);
}

// ---------------------------------------------------------------------------
// Kernel 3: GEMM  H[8192 x 512](bf16) = A[8192 x 1664] @ Wstack[1664 x 512]
// 128x128 tile, BK=32, 512 threads (8 waves 4m x 2n, each 32x64).
// 3-deep prefetch ring: 4 LDS buffer pairs, counted vmcnt (T3+T4 lite).
// ---------------------------------------------------------------------------
__global__ __launch_bounds__(512) void gemm2_kernel(
    const unsigned short* __restrict__ A,
    const unsigned short* __restrict__ wbt,
    unsigned short* __restrict__ H)
{
    __shared__ short lds_a[4][4096];   // 4 bufs x [4 kb][128 row][8] = 32 KB
    __shared__ short lds_b[4][4096];   // 32 KB

    int tid  = threadIdx.x;
    int lane = tid & 63;
    int wid  = tid >> 6;                   // 0..7
    int g    = blockIdx.x;
    int gs   = (g & 7) * 32 + (g >> 3);    // XCD-chunked swizzle (bijective: 256=8*32)
    int tm   = gs >> 2, tn = gs & 3;
    int row0 = tm * 128, col0 = tn * 128;
    int wm   = wid >> 1, wn = wid & 1;     // 4 x 2 waves, each 32 rows x 64 cols
    int r16  = lane & 15, kq = lane >> 4;

    int srow = tid & 127;                  // staging row/col
    int skb  = tid >> 7;                   // staging k-block (0..3)

    f32x4 acc[2][4];
#pragma unroll
    for (int m = 0; m < 2; ++m)
#pragma unroll
        for (int n = 0; n < 4; ++n) acc[m][n] = (f32x4){0.f, 0.f, 0.f, 0.f};

    const unsigned short* ga = A   + (size_t)(row0 + srow) * KDIM + skb * 8;
    const unsigned short* gb = wbt + (size_t)(col0 + srow) * KDIM + skb * 8;

    // wave-uniform LDS staging base (HW adds lane*16B)
    auto stage = [&](int buf, int kt) {
        int k0 = kt * 32;
        __builtin_amdgcn_global_load_lds(
            (const __attribute__((address_space(1))) void*)(ga + k0),
            (__attribute__((address_space(3))) void*)(&lds_a[buf][wid * 512]), 16, 0, 0);
        __builtin_amdgcn_global_load_lds(
            (const __attribute__((address_space(1))) void*)(gb + k0),
            (__attribute__((address_space(3))) void*)(&lds_b[buf][wid * 512]), 16, 0, 0);
    };

    auto compute = [&](int buf) {
        const short* la = &lds_a[buf][0];
        const short* lb = &lds_b[buf][0];
        bf16x8 af[2], bfr[4];
#pragma unroll
        for (int m = 0; m < 2; ++m)
            af[m] = *(const bf16x8*)(la + kq * 1024 + (wm * 32 + m * 16 + r16) * 8);
#pragma unroll
        for (int n = 0; n < 4; ++n)
            bfr[n] = *(const bf16x8*)(lb + kq * 1024 + (wn * 64 + n * 16 + r16) * 8);
#pragma unroll
        for (int m = 0; m < 2; ++m)
#pragma unroll
            for (int n = 0; n < 4; ++n)
                acc[m][n] = __builtin_amdgcn_mfma_f32_16x16x32_bf16(
                    af[m], bfr[n], acc[m][n], 0, 0, 0);
        // pin all body ops before the end-of-iter barrier, then release buffer
        __builtin_amdgcn_sched_barrier(0);
        __builtin_amdgcn_s_barrier();
    };

    // prologue: 3 stages in flight (6 loads)
    stage(0, 0); stage(1, 1); stage(2, 2);

    // main loop: t = 0..48 stages t+3 = 3..51
    for (int t = 0; t < 49; ++t) {
        stage((t + 3) & 3, t + 3);
        asm volatile("s_waitcnt vmcnt(6)" ::: "memory");   // oldest stage (t) done
        __builtin_amdgcn_s_barrier();
        __builtin_amdgcn_sched_barrier(0);
        compute(t & 3);
    }
    // epilogue: t = 49, 50, 51 (no new stages; drain 4 -> 2 -> 0)
    asm volatile("s_waitcnt vmcnt(4)" ::: "memory");
    __builtin_amdgcn_s_barrier();
    __builtin_amdgcn_sched_barrier(0);
    compute(1);
    asm volatile("s_waitcnt vmcnt(2)" ::: "memory");
    __builtin_amdgcn_s_barrier();
    __builtin_amdgcn_sched_barrier(0);
    compute(2);
    asm volatile("s_waitcnt vmcnt(0)" ::: "memory");
    __builtin_amdgcn_s_barrier();
    __builtin_amdgcn_sched_barrier(0);
    compute(3);

    // C/D layout: col = lane&15, row = (lane>>4)*4 + reg; store bf16
#pragma unroll
    for (int m = 0; m < 2; ++m) {
        int grow = row0 + wm * 32 + m * 16 + kq * 4;
#pragma unroll
        for (int n = 0; n < 4; ++n) {
            int gcol = col0 + wn * 64 + n * 16 + r16;
#pragma unroll
            for (int r = 0; r < 4; ++r)
                H[(size_t)(grow + r) * DDIM + gcol] = f2bf(acc[m][n][r]);
        }
    }
}

// ---------------------------------------------------------------------------
// Kernel 4: LayerNorm + relu + residual epilogue. One wave per row. bf16 H in.
// ---------------------------------------------------------------------------
__global__ __launch_bounds__(256) void ln_kernel(
    const unsigned short* __restrict__ H, const float* __restrict__ src,
    const float* __restrict__ sent_mask,
    const float* __restrict__ ln_g, const float* __restrict__ ln_b,
    float* __restrict__ out)
{
    int lane = threadIdx.x & 63;
    int n    = blockIdx.x * 4 + (threadIdx.x >> 6);
    int j0   = lane * 8;

    uint4 hv = *(const uint4*)(H + (size_t)n * DDIM + j0);
    float hs[8]; unpack8(hv, hs);

    float sum = 0.f, sq = 0.f;
#pragma unroll
    for (int i = 0; i < 8; ++i) { sum += hs[i]; sq += hs[i] * hs[i]; }
#pragma unroll
    for (int o = 32; o > 0; o >>= 1) {
        sum += __shfl_xor(sum, o);
        sq  += __shfl_xor(sq, o);
    }
    float mu   = sum * (1.0f / 512.0f);
    float var  = sq * (1.0f / 512.0f) - mu * mu;
    float rstd = rsqrtf(var + 1e-5f);
    float sm   = sent_mask[n];

    float4 gg0 = *(const float4*)(ln_g + j0);
    float4 gg1 = *(const float4*)(ln_g + j0 + 4);
    float4 be0 = *(const float4*)(ln_b + j0);
    float4 be1 = *(const float4*)(ln_b + j0 + 4);
    const float* sr = src + (size_t)n * DDIM + j0;
    float4 s0 = *(const float4*)sr;
    float4 s1 = *(const float4*)(sr + 4);
    float gl[8] = {gg0.x, gg0.y, gg0.z, gg0.w, gg1.x, gg1.y, gg1.z, gg1.w};
    float bt[8] = {be0.x, be0.y, be0.z, be0.w, be1.x, be1.y, be1.z, be1.w};
    float srs[8] = {s0.x, s0.y, s0.z, s0.w, s1.x, s1.y, s1.z, s1.w};

    float o_[8];
#pragma unroll
    for (int i = 0; i < 8; ++i) {
        float v = (hs[i] - mu) * rstd * gl[i] + bt[i];
        v *= sm;
        v = fmaxf(v, 0.f);
        o_[i] = v * sm + srs[i];
    }
    float4 w0 = {o_[0], o_[1], o_[2], o_[3]};
    float4 w1 = {o_[4], o_[5], o_[6], o_[7]};
    float* op = out + (size_t)n * DDIM + j0;
    *(float4*)op = w0;
    *(float4*)(op + 4) = w1;
}

// ---------------------------------------------------------------------------
// Workspace layout (bytes):
//   xb    : 0           (8,388,608)   8192*512 bf16
//   wbt   : 8,388,608   (1,703,936)   512*1664 bf16
//   g_in  : 10,092,544  (32,768)
//   g_out : 10,125,312  (32,768)
//   g_loop: 10,158,080  (32,768)
//   Acat  : 10,190,848  (27,262,976)  8192*1664 bf16
//   H     : 37,453,824  (8,388,608)   8192*512 bf16
// ---------------------------------------------------------------------------
extern "C" void kernel_launch(void* const* d_in, const int* in_sizes, int n_in,
                              void* d_out, int out_size, void* d_ws, size_t ws_size,
                              hipStream_t stream)
{
    const float* src       = (const float*)d_in[0];
    const int*   arc_in    = (const int*)d_in[1];
    const int*   lbl_in    = (const int*)d_in[2];
    const int*   arc_out   = (const int*)d_in[3];
    const int*   lbl_out   = (const int*)d_in[4];
    const float* mask_in   = (const float*)d_in[5];
    const float* mask_out  = (const float*)d_in[6];
    const float* mask_loop = (const float*)d_in[7];
    const float* sent_mask = (const float*)d_in[8];
    const float* V_in      = (const float*)d_in[9];
    const float* b_in      = (const float*)d_in[10];
    const float* Vg_in     = (const float*)d_in[11];
    const float* bg_in     = (const float*)d_in[12];
    const float* V_out     = (const float*)d_in[13];
    const float* b_out     = (const float*)d_in[14];
    const float* Vg_out    = (const float*)d_in[15];
    const float* bg_out    = (const float*)d_in[16];
    const float* W_loop    = (const float*)d_in[17];
    const float* Wg_loop   = (const float*)d_in[18];
    const float* ln_g      = (const float*)d_in[19];
    const float* ln_b      = (const float*)d_in[20];

    uint8_t* ws = (uint8_t*)d_ws;
    unsigned short* xb    = (unsigned short*)(ws);
    unsigned short* wbt   = (unsigned short*)(ws + 8388608);
    float*          g_in  = (float*)(ws + 10092544);
    float*          g_out = (float*)(ws + 10125312);
    float*          g_lp  = (float*)(ws + 10158080);
    unsigned short* Acat  = (unsigned short*)(ws + 10190848);
    unsigned short* H     = (unsigned short*)(ws + 37453824);

    prep_kernel<<<2256, 256, 0, stream>>>(src, Vg_in, Vg_out, Wg_loop,
                                          V_in, V_out, W_loop, b_in, b_out,
                                          xb, wbt, g_in, g_out, g_lp);
    aggx_kernel<<<2048, 256, 0, stream>>>(xb, g_in, g_out, g_lp,
                                          arc_in, lbl_in, arc_out, lbl_out,
                                          mask_in, mask_out, mask_loop,
                                          bg_in, bg_out, Acat);
    gemm2_kernel<<<256, 512, 0, stream>>>(Acat, wbt, H);
    ln_kernel<<<2048, 256, 0, stream>>>(H, src, sent_mask, ln_g, ln_b, (float*)d_out);
}